// Round 2
// baseline (283.314 us; speedup 1.0000x reference)
//
#include <hip/hip_runtime.h>

// ACELoss3D round 2: z-vectorized (float4, 4 elems/thread/iter) fused 19-point
// stencil + region term; single kernel with atomic partial sums + last-block
// finish. All boundary cases are clamped-index central differences.
//
// ws layout: ws[0..2] = float sums S1,S2,S3; ws[3] = uint done-counter.
// Zeroed每 launch via hipMemsetAsync(16B) on the stream (graph-capture safe).

static constexpr int   NTOT   = 6 * 128 * 128 * 128;   // 12,582,912
static constexpr int   NG     = NTOT / 4;              // 3,145,728 float4 groups
static constexpr int   NBLK   = 3072;                  // 3072*256*4 == NTOT exactly
static constexpr float ALPHA_ = 0.001f;
static constexpr float MIU_   = 1.0f;
static constexpr float EPS_   = 1e-8f;

__device__ __forceinline__ void wave_reduce3(float& a, float& b, float& c) {
#pragma unroll
  for (int off = 32; off > 0; off >>= 1) {
    a += __shfl_down(a, off);
    b += __shfl_down(b, off);
    c += __shfl_down(c, off);
  }
}

__global__ __launch_bounds__(256) void ace_main(
    const float* __restrict__ pred, const float* __restrict__ truth,
    float* __restrict__ sums, unsigned* __restrict__ cnt,
    float* __restrict__ out) {
  const int tid = threadIdx.x;
  float s1 = 0.f, s2 = 0.f, s3 = 0.f;

  for (int g = blockIdx.x * 256 + tid; g < NG; g += NBLK * 256) {
    const int z0 = (g & 31) << 2;          // 0,4,...,124
    const int y  = (g >> 5) & 127;
    const int x  = (g >> 12) & 127;
    const size_t base = ((size_t)(g >> 19)) << 21;
    const float* __restrict__ bp = pred + base;

    const int zmi = z0 ? z0 - 1 : 0;
    const int zpi = (z0 < 124) ? z0 + 4 : 127;
    const int rC  = y << 7;
    const int rYp = ((y < 127) ? y + 1 : 127) << 7;
    const int rYm = ((y > 0)   ? y - 1 : 0)   << 7;
    const int pC  = x << 14;
    const int pXp = ((x < 127) ? x + 1 : 127) << 14;
    const int pXm = ((x > 0)   ? x - 1 : 0)   << 14;

    // 5 columns needing z-1..z+4 (6 floats: clamped lo, float4, clamped hi)
    const float* cC  = bp + pC  + rC;
    const float* cXP = bp + pXp + rC;
    const float* cXM = bp + pXm + rC;
    const float* cYP = bp + pC  + rYp;
    const float* cYM = bp + pC  + rYm;
    const float4 vC  = *(const float4*)(cC  + z0);
    const float4 vXP = *(const float4*)(cXP + z0);
    const float4 vXM = *(const float4*)(cXM + z0);
    const float4 vYP = *(const float4*)(cYP + z0);
    const float4 vYM = *(const float4*)(cYM + z0);
    const float colC [6] = {cC [zmi], vC.x,  vC.y,  vC.z,  vC.w,  cC [zpi]};
    const float colXP[6] = {cXP[zmi], vXP.x, vXP.y, vXP.z, vXP.w, cXP[zpi]};
    const float colXM[6] = {cXM[zmi], vXM.x, vXM.y, vXM.z, vXM.w, cXM[zpi]};
    const float colYP[6] = {cYP[zmi], vYP.x, vYP.y, vYP.z, vYP.w, cYP[zpi]};
    const float colYM[6] = {cYM[zmi], vYM.x, vYM.y, vYM.z, vYM.w, cYM[zpi]};

    // 4 corner columns, z only
    const float4 vPP = *(const float4*)(bp + pXp + rYp + z0);
    const float4 vMP = *(const float4*)(bp + pXm + rYp + z0);
    const float4 vPM = *(const float4*)(bp + pXp + rYm + z0);
    const float4 vMM = *(const float4*)(bp + pXm + rYm + z0);
    const float aPP[4] = {vPP.x, vPP.y, vPP.z, vPP.w};
    const float aMP[4] = {vMP.x, vMP.y, vMP.z, vMP.w};
    const float aPM[4] = {vPM.x, vPM.y, vPM.z, vPM.w};
    const float aMM[4] = {vMM.x, vMM.y, vMM.z, vMM.w};

    const float4 t4 = *(const float4*)(truth + base + pC + rC + z0);
    const float aT[4] = {t4.x, t4.y, t4.z, t4.w};

#pragma unroll
    for (int e = 0; e < 4; ++e) {
      const float u0  = colC[e + 1];
      const float uzm = colC[e];
      const float uzp = colC[e + 2];
      const float uxp = colXP[e + 1], uxm = colXM[e + 1];
      const float uyp = colYP[e + 1], uym = colYM[e + 1];

      // un-halved first differences (fold 0.5 into constants)
      const float Di = uxp - uxm;
      const float Dj = uyp - uym;
      const float Dk = uzp - uzm;
      const float ci2 = 0.25f * Di * Di;
      const float cj2 = 0.25f * Dj * Dj;
      const float ck2 = 0.25f * Dk * Dk;
      const float cii = uxp + uxm - 2.f * u0;
      const float cjj = uyp + uym - 2.f * u0;
      const float ckk = uzp + uzm - 2.f * u0;
      // mixed (un-halved): cij = Dij/2 etc.; 2*cik*cjk*cij = 0.25*Dik*Djk*Dij
      const float Dij = (aPP[e] - aMP[e]) - (aPM[e] - aMM[e]);
      const float Dik = (colXP[e + 2] - colXM[e + 2]) - (colXP[e] - colXM[e]);
      const float Djk = (colYP[e + 2] - colYM[e + 2]) - (colYP[e] - colYM[e]);

      const float ss = ci2 + cj2 + ck2;
      const float curv = (1.f + ci2 + cj2) * ckk + (1.f + cj2 + ck2) * cii +
                         (1.f + ci2 + ck2) * cjj - 0.25f * Dik * Djk * Dij;
      const float length = sqrtf(EPS_ + ss);
      // (sqrt(1+ss)+1e-8)^2 ~= 1+ss  (rel err ~2e-8, threshold is ~2%)
      s3 += ALPHA_ + curv * curv * length * __builtin_amdgcn_rcpf(1.f + ss);

      const float t = aT[e];
      const float tm1 = t - 1.f;
      s1 += u0 * (tm1 * tm1);
      s2 += (1.f - u0) * (t * t);
    }
  }

  wave_reduce3(s1, s2, s3);
  __shared__ float l1[4], l2[4], l3[4];
  const int lane = tid & 63, wv = tid >> 6;
  if (lane == 0) { l1[wv] = s1; l2[wv] = s2; l3[wv] = s3; }
  __syncthreads();
  if (tid == 0) {
    atomicAdd(&sums[0], l1[0] + l1[1] + l1[2] + l1[3]);
    atomicAdd(&sums[1], l2[0] + l2[1] + l2[2] + l2[3]);
    atomicAdd(&sums[2], l3[0] + l3[1] + l3[2] + l3[3]);
    __threadfence();
    const unsigned old = atomicAdd(cnt, 1u);
    if (old == (unsigned)(gridDim.x - 1)) {
      // last block: all other adds are globally visible (fence-before-count);
      // read via atomic RMW to bypass any stale cache.
      const float S1 = atomicAdd(&sums[0], 0.f);
      const float S2 = atomicAdd(&sums[1], 0.f);
      const float S3 = atomicAdd(&sums[2], 0.f);
      out[0] = MIU_ * fabsf(S1) + fabsf(S2) + S3;
    }
  }
}

extern "C" void kernel_launch(void* const* d_in, const int* in_sizes, int n_in,
                              void* d_out, int out_size, void* d_ws, size_t ws_size,
                              hipStream_t stream) {
  const float* pred  = (const float*)d_in[0];   // y_pred
  const float* truth = (const float*)d_in[1];   // y_true
  float* out = (float*)d_out;
  float* sums = (float*)d_ws;
  unsigned* cnt = (unsigned*)d_ws + 3;

  hipMemsetAsync(d_ws, 0, 16, stream);          // zero sums + counter
  ace_main<<<NBLK, 256, 0, stream>>>(pred, truth, sums, cnt, out);
}

// Round 3
// 272.274 us; speedup vs baseline: 1.0405x; 1.0405x over previous
//
#include <hip/hip_runtime.h>

// ACELoss3D round 3: float4 z-vectorization with NO local arrays (R2's arrays
// went to scratch: WRITE_SIZE 121->384MB, VALUBusy 86->14%). All fragments are
// named scalars; early combines (XP+-XM, YP+-YM, corner double-diffs) cap
// liveness at ~35 floats. Approx sqrt/rcp (threshold 2%); ALPHA hoisted.

static constexpr int   NTOT   = 6 * 128 * 128 * 128;   // 12,582,912
static constexpr int   NG     = NTOT / 4;              // 3,145,728 groups
static constexpr int   NBLK   = 3072;                  // 4 grid-stride iters
static constexpr float ALPHA_ = 0.001f;
static constexpr float MIU_   = 1.0f;
static constexpr float EPS_   = 1e-8f;

__device__ __forceinline__ void wave_reduce3(float& a, float& b, float& c) {
#pragma unroll
  for (int off = 32; off > 0; off >>= 1) {
    a += __shfl_down(a, off);
    b += __shfl_down(b, off);
    c += __shfl_down(c, off);
  }
}

// One output element. di/dj = un-halved first diffs; sx/sy = uxp+uxm, uyp+uym;
// dik/djk/dij = un-halved mixed double-diffs. 2*cik*cjk*cij = 0.25*dik*djk*dij.
__device__ __forceinline__ void elem(
    float uzm, float u0, float uzp,
    float di, float sx, float dj, float sy,
    float dik, float djk, float dij,
    float t, float& s1, float& s2, float& s3) {
  const float dk  = uzp - uzm;
  const float ci2 = 0.25f * di * di;
  const float cj2 = 0.25f * dj * dj;
  const float ck2 = 0.25f * dk * dk;
  const float u2  = u0 + u0;
  const float cii = sx - u2;
  const float cjj = sy - u2;
  const float ckk = (uzp + uzm) - u2;
  const float ss  = ci2 + cj2 + ck2;
  const float ss1 = 1.f + ss;
  // (1+ss-ck2)*ckk + (1+ss-ci2)*cii + (1+ss-cj2)*cjj
  //   = ss1*(cii+cjj+ckk) - (ci2*cii + cj2*cjj + ck2*ckk)
  const float L = (cii + cjj) + ckk;
  const float M = fmaf(ci2, cii, fmaf(cj2, cjj, ck2 * ckk));
  float curv = fmaf(ss1, L, -M);
  curv = fmaf(-0.25f * dij, dik * djk, curv);
  // |curv|^2 * sqrt(eps+ss) / (sqrt(1+ss)+1e-8)^2 ; denom ~= (1+ss) (rel 2e-8)
  const float len = __builtin_amdgcn_sqrtf(EPS_ + ss);
  s3 = fmaf(curv * curv, len * __builtin_amdgcn_rcpf(ss1), s3);
  const float tm1 = t - 1.f;
  s1 = fmaf(u0, tm1 * tm1, s1);
  s2 = fmaf(1.f - u0, t * t, s2);
}

__global__ __launch_bounds__(256, 4) void ace_main(
    const float* __restrict__ pred, const float* __restrict__ truth,
    float* __restrict__ sums, unsigned* __restrict__ cnt,
    float* __restrict__ out) {
  const int tid = threadIdx.x;
  float s1 = 0.f, s2 = 0.f, s3 = 0.f;

  for (int g = blockIdx.x * 256 + tid; g < NG; g += NBLK * 256) {
    const int z0 = (g & 31) << 2;          // 0,4,...,124
    const int y  = (g >> 5) & 127;
    const int x  = (g >> 12) & 127;
    const size_t base = ((size_t)(g >> 19)) << 21;
    const float* __restrict__ bp = pred + base;

    const int zmi = z0 ? z0 - 1 : 0;
    const int zpi = (z0 < 124) ? z0 + 4 : 127;
    const int rC  = y << 7;
    const int rYp = ((y < 127) ? y + 1 : 127) << 7;
    const int rYm = ((y > 0)   ? y - 1 : 0)   << 7;
    const int pC  = x << 14;
    const int pXp = ((x < 127) ? x + 1 : 127) << 14;
    const int pXm = ((x > 0)   ? x - 1 : 0)   << 14;

    const float* cC  = bp + pC  + rC;
    const float* cXP = bp + pXp + rC;
    const float* cXM = bp + pXm + rC;
    const float* cYP = bp + pC  + rYp;
    const float* cYM = bp + pC  + rYm;

    const float4 vC  = *(const float4*)(cC  + z0);
    const float  clo = cC[zmi],  chi = cC[zpi];
    const float4 vXP = *(const float4*)(cXP + z0);
    const float4 vXM = *(const float4*)(cXM + z0);
    const float  xplo = cXP[zmi], xphi = cXP[zpi];
    const float  xmlo = cXM[zmi], xmhi = cXM[zpi];
    const float4 vYP = *(const float4*)(cYP + z0);
    const float4 vYM = *(const float4*)(cYM + z0);
    const float  yplo = cYP[zmi], yphi = cYP[zpi];
    const float  ymlo = cYM[zmi], ymhi = cYM[zpi];
    const float4 vPP = *(const float4*)(bp + pXp + rYp + z0);
    const float4 vMP = *(const float4*)(bp + pXm + rYp + z0);
    const float4 vPM = *(const float4*)(bp + pXp + rYm + z0);
    const float4 vMM = *(const float4*)(bp + pXm + rYm + z0);
    const float4 t4  = *(const float4*)(truth + base + pC + rC + z0);

    // Early combines — originals die here, liveness stays bounded.
    const float dx0 = xplo  - xmlo;
    const float dx1 = vXP.x - vXM.x;
    const float dx2 = vXP.y - vXM.y;
    const float dx3 = vXP.z - vXM.z;
    const float dx4 = vXP.w - vXM.w;
    const float dx5 = xphi  - xmhi;
    const float sx1 = vXP.x + vXM.x;
    const float sx2 = vXP.y + vXM.y;
    const float sx3 = vXP.z + vXM.z;
    const float sx4 = vXP.w + vXM.w;

    const float dy0 = yplo  - ymlo;
    const float dy1 = vYP.x - vYM.x;
    const float dy2 = vYP.y - vYM.y;
    const float dy3 = vYP.z - vYM.z;
    const float dy4 = vYP.w - vYM.w;
    const float dy5 = yphi  - ymhi;
    const float sy1 = vYP.x + vYM.x;
    const float sy2 = vYP.y + vYM.y;
    const float sy3 = vYP.z + vYM.z;
    const float sy4 = vYP.w + vYM.w;

    const float j0 = (vPP.x - vMP.x) - (vPM.x - vMM.x);
    const float j1 = (vPP.y - vMP.y) - (vPM.y - vMM.y);
    const float j2 = (vPP.z - vMP.z) - (vPM.z - vMM.z);
    const float j3 = (vPP.w - vMP.w) - (vPM.w - vMM.w);

    elem(clo,  vC.x, vC.y, dx1, sx1, dy1, sy1, dx2 - dx0, dy2 - dy0, j0, t4.x, s1, s2, s3);
    elem(vC.x, vC.y, vC.z, dx2, sx2, dy2, sy2, dx3 - dx1, dy3 - dy1, j1, t4.y, s1, s2, s3);
    elem(vC.y, vC.z, vC.w, dx3, sx3, dy3, sy3, dx4 - dx2, dy4 - dy2, j2, t4.z, s1, s2, s3);
    elem(vC.z, vC.w, chi,  dx4, sx4, dy4, sy4, dx5 - dx3, dy5 - dy3, j3, t4.w, s1, s2, s3);
  }

  wave_reduce3(s1, s2, s3);
  __shared__ float l1[4], l2[4], l3[4];
  const int lane = tid & 63, wv = tid >> 6;
  if (lane == 0) { l1[wv] = s1; l2[wv] = s2; l3[wv] = s3; }
  __syncthreads();
  if (tid == 0) {
    atomicAdd(&sums[0], l1[0] + l1[1] + l1[2] + l1[3]);
    atomicAdd(&sums[1], l2[0] + l2[1] + l2[2] + l2[3]);
    atomicAdd(&sums[2], l3[0] + l3[1] + l3[2] + l3[3]);
    __threadfence();
    const unsigned old = atomicAdd(cnt, 1u);
    if (old == (unsigned)(gridDim.x - 1)) {
      const float S1 = atomicAdd(&sums[0], 0.f);
      const float S2 = atomicAdd(&sums[1], 0.f);
      const float S3 = atomicAdd(&sums[2], 0.f);
      // ALPHA hoisted: + ALPHA_*NTOT once.
      out[0] = MIU_ * fabsf(S1) + fabsf(S2) + S3 + ALPHA_ * (float)NTOT;
    }
  }
}

extern "C" void kernel_launch(void* const* d_in, const int* in_sizes, int n_in,
                              void* d_out, int out_size, void* d_ws, size_t ws_size,
                              hipStream_t stream) {
  const float* pred  = (const float*)d_in[0];   // y_pred
  const float* truth = (const float*)d_in[1];   // y_true
  float* out = (float*)d_out;
  float* sums = (float*)d_ws;
  unsigned* cnt = (unsigned*)d_ws + 3;

  hipMemsetAsync(d_ws, 0, 16, stream);          // zero sums + counter
  ace_main<<<NBLK, 256, 0, stream>>>(pred, truth, sums, cnt, out);
}

// Round 4
// 141.315 us; speedup vs baseline: 2.0048x; 1.9267x over previous
//
#include <hip/hip_runtime.h>

// ACELoss3D round 4: R3's float4 math, but NO contended atomics.
// R2/R3 regression root cause: 3072 blocks x 4 device-scope RMWs to ONE cache
// line (sums[0..2]+cnt) serialized across 8 XCDs (~125us, caching-independent,
// invisible in VALU/HBM counters). Back to distinct-address per-block partials
// + tiny finish kernel. Also: no grid-stride loop -- 12288 blocks, one
// 4-element group per thread, so all ~21 loads issue independently (max MLP).

static constexpr int   NTOT   = 6 * 128 * 128 * 128;   // 12,582,912
static constexpr int   NG     = NTOT / 4;              // 3,145,728 groups
static constexpr int   NBLK   = 12288;                 // NBLK*256 == NG exactly
static constexpr float ALPHA_ = 0.001f;
static constexpr float MIU_   = 1.0f;
static constexpr float EPS_   = 1e-8f;

__device__ __forceinline__ void wave_reduce3(float& a, float& b, float& c) {
#pragma unroll
  for (int off = 32; off > 0; off >>= 1) {
    a += __shfl_down(a, off);
    b += __shfl_down(b, off);
    c += __shfl_down(c, off);
  }
}

// One output element. di/dj = un-halved first diffs; sx/sy = uxp+uxm, uyp+uym;
// dik/djk/dij = un-halved mixed double-diffs. 2*cik*cjk*cij = 0.25*dik*djk*dij.
__device__ __forceinline__ void elem(
    float uzm, float u0, float uzp,
    float di, float sx, float dj, float sy,
    float dik, float djk, float dij,
    float t, float& s1, float& s2, float& s3) {
  const float dk  = uzp - uzm;
  const float ci2 = 0.25f * di * di;
  const float cj2 = 0.25f * dj * dj;
  const float ck2 = 0.25f * dk * dk;
  const float u2  = u0 + u0;
  const float cii = sx - u2;
  const float cjj = sy - u2;
  const float ckk = (uzp + uzm) - u2;
  const float ss  = ci2 + cj2 + ck2;
  const float ss1 = 1.f + ss;
  const float L = (cii + cjj) + ckk;
  const float M = fmaf(ci2, cii, fmaf(cj2, cjj, ck2 * ckk));
  float curv = fmaf(ss1, L, -M);
  curv = fmaf(-0.25f * dij, dik * djk, curv);
  const float len = __builtin_amdgcn_sqrtf(EPS_ + ss);
  s3 = fmaf(curv * curv, len * __builtin_amdgcn_rcpf(ss1), s3);
  const float tm1 = t - 1.f;
  s1 = fmaf(u0, tm1 * tm1, s1);
  s2 = fmaf(1.f - u0, t * t, s2);
}

__global__ __launch_bounds__(256) void ace_main(
    const float* __restrict__ pred, const float* __restrict__ truth,
    float* __restrict__ partials) {
  const int tid = threadIdx.x;
  const int g = blockIdx.x * 256 + tid;            // 0..NG-1, exact cover

  const int z0 = (g & 31) << 2;                    // 0,4,...,124
  const int y  = (g >> 5) & 127;
  const int x  = (g >> 12) & 127;
  const size_t base = ((size_t)(g >> 19)) << 21;
  const float* __restrict__ bp = pred + base;

  const int zmi = z0 ? z0 - 1 : 0;
  const int zpi = (z0 < 124) ? z0 + 4 : 127;
  const int rC  = y << 7;
  const int rYp = ((y < 127) ? y + 1 : 127) << 7;
  const int rYm = ((y > 0)   ? y - 1 : 0)   << 7;
  const int pC  = x << 14;
  const int pXp = ((x < 127) ? x + 1 : 127) << 14;
  const int pXm = ((x > 0)   ? x - 1 : 0)   << 14;

  const float* cC  = bp + pC  + rC;
  const float* cXP = bp + pXp + rC;
  const float* cXM = bp + pXm + rC;
  const float* cYP = bp + pC  + rYp;
  const float* cYM = bp + pC  + rYm;

  const float4 vC  = *(const float4*)(cC  + z0);
  const float  clo = cC[zmi],  chi = cC[zpi];
  const float4 vXP = *(const float4*)(cXP + z0);
  const float4 vXM = *(const float4*)(cXM + z0);
  const float  xplo = cXP[zmi], xphi = cXP[zpi];
  const float  xmlo = cXM[zmi], xmhi = cXM[zpi];
  const float4 vYP = *(const float4*)(cYP + z0);
  const float4 vYM = *(const float4*)(cYM + z0);
  const float  yplo = cYP[zmi], yphi = cYP[zpi];
  const float  ymlo = cYM[zmi], ymhi = cYM[zpi];
  const float4 vPP = *(const float4*)(bp + pXp + rYp + z0);
  const float4 vMP = *(const float4*)(bp + pXm + rYp + z0);
  const float4 vPM = *(const float4*)(bp + pXp + rYm + z0);
  const float4 vMM = *(const float4*)(bp + pXm + rYm + z0);
  const float4 t4  = *(const float4*)(truth + base + pC + rC + z0);

  // Early combines — originals die here, liveness stays bounded.
  const float dx0 = xplo  - xmlo;
  const float dx1 = vXP.x - vXM.x;
  const float dx2 = vXP.y - vXM.y;
  const float dx3 = vXP.z - vXM.z;
  const float dx4 = vXP.w - vXM.w;
  const float dx5 = xphi  - xmhi;
  const float sx1 = vXP.x + vXM.x;
  const float sx2 = vXP.y + vXM.y;
  const float sx3 = vXP.z + vXM.z;
  const float sx4 = vXP.w + vXM.w;

  const float dy0 = yplo  - ymlo;
  const float dy1 = vYP.x - vYM.x;
  const float dy2 = vYP.y - vYM.y;
  const float dy3 = vYP.z - vYM.z;
  const float dy4 = vYP.w - vYM.w;
  const float dy5 = yphi  - ymhi;
  const float sy1 = vYP.x + vYM.x;
  const float sy2 = vYP.y + vYM.y;
  const float sy3 = vYP.z + vYM.z;
  const float sy4 = vYP.w + vYM.w;

  const float j0 = (vPP.x - vMP.x) - (vPM.x - vMM.x);
  const float j1 = (vPP.y - vMP.y) - (vPM.y - vMM.y);
  const float j2 = (vPP.z - vMP.z) - (vPM.z - vMM.z);
  const float j3 = (vPP.w - vMP.w) - (vPM.w - vMM.w);

  float s1 = 0.f, s2 = 0.f, s3 = 0.f;
  elem(clo,  vC.x, vC.y, dx1, sx1, dy1, sy1, dx2 - dx0, dy2 - dy0, j0, t4.x, s1, s2, s3);
  elem(vC.x, vC.y, vC.z, dx2, sx2, dy2, sy2, dx3 - dx1, dy3 - dy1, j1, t4.y, s1, s2, s3);
  elem(vC.y, vC.z, vC.w, dx3, sx3, dy3, sy3, dx4 - dx2, dy4 - dy2, j2, t4.z, s1, s2, s3);
  elem(vC.z, vC.w, chi,  dx4, sx4, dy4, sy4, dx5 - dx3, dy5 - dy3, j3, t4.w, s1, s2, s3);

  wave_reduce3(s1, s2, s3);
  __shared__ float l1[4], l2[4], l3[4];
  const int lane = tid & 63, wv = tid >> 6;
  if (lane == 0) { l1[wv] = s1; l2[wv] = s2; l3[wv] = s3; }
  __syncthreads();
  if (tid == 0) {
    // SoA partials at DISTINCT addresses — no atomics, no contention.
    partials[blockIdx.x]            = l1[0] + l1[1] + l1[2] + l1[3];
    partials[NBLK + blockIdx.x]     = l2[0] + l2[1] + l2[2] + l2[3];
    partials[2 * NBLK + blockIdx.x] = l3[0] + l3[1] + l3[2] + l3[3];
  }
}

__global__ __launch_bounds__(1024) void ace_final(
    const float* __restrict__ partials, float* __restrict__ out) {
  const int tid = threadIdx.x;
  float s1 = 0.f, s2 = 0.f, s3 = 0.f;
  // NBLK floats per sum, read as float4 (NBLK/4 = 3072 vectors, 1024 thr -> 3 each)
  const float4* p1 = (const float4*)(partials);
  const float4* p2 = (const float4*)(partials + NBLK);
  const float4* p3 = (const float4*)(partials + 2 * NBLK);
#pragma unroll
  for (int i = 0; i < NBLK / 4 / 1024; ++i) {
    const float4 a = p1[i * 1024 + tid];
    const float4 b = p2[i * 1024 + tid];
    const float4 c = p3[i * 1024 + tid];
    s1 += (a.x + a.y) + (a.z + a.w);
    s2 += (b.x + b.y) + (b.z + b.w);
    s3 += (c.x + c.y) + (c.z + c.w);
  }
  wave_reduce3(s1, s2, s3);
  __shared__ float l1[16], l2[16], l3[16];
  const int lane = tid & 63, wv = tid >> 6;
  if (lane == 0) { l1[wv] = s1; l2[wv] = s2; l3[wv] = s3; }
  __syncthreads();
  if (tid == 0) {
    float S1 = 0.f, S2 = 0.f, S3 = 0.f;
#pragma unroll
    for (int w = 0; w < 16; ++w) { S1 += l1[w]; S2 += l2[w]; S3 += l3[w]; }
    out[0] = MIU_ * fabsf(S1) + fabsf(S2) + S3 + ALPHA_ * (float)NTOT;
  }
}

extern "C" void kernel_launch(void* const* d_in, const int* in_sizes, int n_in,
                              void* d_out, int out_size, void* d_ws, size_t ws_size,
                              hipStream_t stream) {
  const float* pred  = (const float*)d_in[0];   // y_pred
  const float* truth = (const float*)d_in[1];   // y_true
  float* out      = (float*)d_out;
  float* partials = (float*)d_ws;               // 3*NBLK floats = 147 KB

  ace_main<<<NBLK, 256, 0, stream>>>(pred, truth, partials);
  ace_final<<<1, 1024, 0, stream>>>(partials, out);
}

// Round 5
// 125.234 us; speedup vs baseline: 2.2623x; 1.1284x over previous
//
#include <hip/hip_runtime.h>

// ACELoss3D round 5: replace all 10 clamped-scalar z-boundary loads with 6
// cross-lane shuffles + selects. Lane i's z0-1 value == lane i-1's vC.w (lanes
// are consecutive z-groups), and the dx/dy combine needed at z0-1 / z0+4 is
// lane -/+1's dx.w / dx.x. Clamp lanes (z0==0 -> lanes 0,32; z0==124 -> lanes
// 31,63) are wave-internal and fixed by select to own .x/.w. This halves VMEM
// instructions (21->11/thread) and L1 line-transactions per wave.
// Two-kernel reduction (distinct-address partials) kept from R4 — the R2/R3
// single-line atomic contention cost ~125us.

static constexpr int   NTOT   = 6 * 128 * 128 * 128;   // 12,582,912
static constexpr int   NG     = NTOT / 4;              // 3,145,728 groups
static constexpr int   NBLK   = 12288;                 // NBLK*256 == NG exactly
static constexpr float ALPHA_ = 0.001f;
static constexpr float MIU_   = 1.0f;
static constexpr float EPS_   = 1e-8f;

__device__ __forceinline__ void wave_reduce3(float& a, float& b, float& c) {
#pragma unroll
  for (int off = 32; off > 0; off >>= 1) {
    a += __shfl_down(a, off);
    b += __shfl_down(b, off);
    c += __shfl_down(c, off);
  }
}

// One output element. di/dj = un-halved first diffs; sx/sy = uxp+uxm, uyp+uym;
// dik/djk/dij = un-halved mixed double-diffs. 2*cik*cjk*cij = 0.25*dik*djk*dij.
__device__ __forceinline__ void elem(
    float uzm, float u0, float uzp,
    float di, float sx, float dj, float sy,
    float dik, float djk, float dij,
    float t, float& s1, float& s2, float& s3) {
  const float dk  = uzp - uzm;
  const float ci2 = 0.25f * di * di;
  const float cj2 = 0.25f * dj * dj;
  const float ck2 = 0.25f * dk * dk;
  const float u2  = u0 + u0;
  const float cii = sx - u2;
  const float cjj = sy - u2;
  const float ckk = (uzp + uzm) - u2;
  const float ss  = ci2 + cj2 + ck2;
  const float ss1 = 1.f + ss;
  const float L = (cii + cjj) + ckk;
  const float M = fmaf(ci2, cii, fmaf(cj2, cjj, ck2 * ckk));
  float curv = fmaf(ss1, L, -M);
  curv = fmaf(-0.25f * dij, dik * djk, curv);
  const float len = __builtin_amdgcn_sqrtf(EPS_ + ss);
  s3 = fmaf(curv * curv, len * __builtin_amdgcn_rcpf(ss1), s3);
  const float tm1 = t - 1.f;
  s1 = fmaf(u0, tm1 * tm1, s1);
  s2 = fmaf(1.f - u0, t * t, s2);
}

__global__ __launch_bounds__(256) void ace_main(
    const float* __restrict__ pred, const float* __restrict__ truth,
    float* __restrict__ partials) {
  const int tid = threadIdx.x;
  const int g = blockIdx.x * 256 + tid;            // 0..NG-1, exact cover

  const int z0 = (g & 31) << 2;                    // 0,4,...,124
  const int y  = (g >> 5) & 127;
  const int x  = (g >> 12) & 127;
  const size_t base = ((size_t)(g >> 19)) << 21;
  const float* __restrict__ bp = pred + base;

  const int rC  = y << 7;
  const int rYp = ((y < 127) ? y + 1 : 127) << 7;
  const int rYm = ((y > 0)   ? y - 1 : 0)   << 7;
  const int pC  = x << 14;
  const int pXp = ((x < 127) ? x + 1 : 127) << 14;
  const int pXm = ((x > 0)   ? x - 1 : 0)   << 14;

  // 10 float4 loads — the ONLY vector-memory reads in the kernel.
  const float4 vC  = *(const float4*)(bp + pC  + rC  + z0);
  const float4 vXP = *(const float4*)(bp + pXp + rC  + z0);
  const float4 vXM = *(const float4*)(bp + pXm + rC  + z0);
  const float4 vYP = *(const float4*)(bp + pC  + rYp + z0);
  const float4 vYM = *(const float4*)(bp + pC  + rYm + z0);
  const float4 vPP = *(const float4*)(bp + pXp + rYp + z0);
  const float4 vMP = *(const float4*)(bp + pXm + rYp + z0);
  const float4 vPM = *(const float4*)(bp + pXp + rYm + z0);
  const float4 vMM = *(const float4*)(bp + pXm + rYm + z0);
  const float4 t4  = *(const float4*)(truth + base + pC + rC + z0);

  // Early combines.
  const float dxa = vXP.x - vXM.x, dxb = vXP.y - vXM.y;
  const float dxc = vXP.z - vXM.z, dxd = vXP.w - vXM.w;
  const float sxa = vXP.x + vXM.x, sxb = vXP.y + vXM.y;
  const float sxc = vXP.z + vXM.z, sxd = vXP.w + vXM.w;
  const float dya = vYP.x - vYM.x, dyb = vYP.y - vYM.y;
  const float dyc = vYP.z - vYM.z, dyd = vYP.w - vYM.w;
  const float sya = vYP.x + vYM.x, syb = vYP.y + vYM.y;
  const float syc = vYP.z + vYM.z, syd = vYP.w + vYM.w;
  const float ja = (vPP.x - vMP.x) - (vPM.x - vMM.x);
  const float jb = (vPP.y - vMP.y) - (vPM.y - vMM.y);
  const float jc = (vPP.z - vMP.z) - (vPM.z - vMM.z);
  const float jd = (vPP.w - vMP.w) - (vPM.w - vMM.w);

  // z-boundary values from adjacent lanes (lane i-1 holds z0-4..z0-1).
  // Clamp lanes: z0==0 (lanes 0,32): z-1 -> z=0 (own .x); z0==124 (lanes
  // 31,63): z+4 -> z=127 (own .w). Shuffles never cross the wave.
  const bool zlo = (z0 == 0), zhi = (z0 == 124);
  float clo  = __shfl_up  (vC.w, 1);  clo  = zlo ? vC.x : clo;
  float chi  = __shfl_down(vC.x, 1);  chi  = zhi ? vC.w : chi;
  float dxm1 = __shfl_up  (dxd, 1);   dxm1 = zlo ? dxa : dxm1;
  float dxp4 = __shfl_down(dxa, 1);   dxp4 = zhi ? dxd : dxp4;
  float dym1 = __shfl_up  (dyd, 1);   dym1 = zlo ? dya : dym1;
  float dyp4 = __shfl_down(dya, 1);   dyp4 = zhi ? dyd : dyp4;

  float s1 = 0.f, s2 = 0.f, s3 = 0.f;
  elem(clo,  vC.x, vC.y, dxa, sxa, dya, sya, dxb - dxm1, dyb - dym1, ja, t4.x, s1, s2, s3);
  elem(vC.x, vC.y, vC.z, dxb, sxb, dyb, syb, dxc - dxa,  dyc - dya,  jb, t4.y, s1, s2, s3);
  elem(vC.y, vC.z, vC.w, dxc, sxc, dyc, syc, dxd - dxb,  dyd - dyb,  jc, t4.z, s1, s2, s3);
  elem(vC.z, vC.w, chi,  dxd, sxd, dyd, syd, dxp4 - dxc, dyp4 - dyc, jd, t4.w, s1, s2, s3);

  wave_reduce3(s1, s2, s3);
  __shared__ float l1[4], l2[4], l3[4];
  const int lane = tid & 63, wv = tid >> 6;
  if (lane == 0) { l1[wv] = s1; l2[wv] = s2; l3[wv] = s3; }
  __syncthreads();
  if (tid == 0) {
    partials[blockIdx.x]            = l1[0] + l1[1] + l1[2] + l1[3];
    partials[NBLK + blockIdx.x]     = l2[0] + l2[1] + l2[2] + l2[3];
    partials[2 * NBLK + blockIdx.x] = l3[0] + l3[1] + l3[2] + l3[3];
  }
}

__global__ __launch_bounds__(1024) void ace_final(
    const float* __restrict__ partials, float* __restrict__ out) {
  const int tid = threadIdx.x;
  float s1 = 0.f, s2 = 0.f, s3 = 0.f;
  const float4* p1 = (const float4*)(partials);
  const float4* p2 = (const float4*)(partials + NBLK);
  const float4* p3 = (const float4*)(partials + 2 * NBLK);
#pragma unroll
  for (int i = 0; i < NBLK / 4 / 1024; ++i) {
    const float4 a = p1[i * 1024 + tid];
    const float4 b = p2[i * 1024 + tid];
    const float4 c = p3[i * 1024 + tid];
    s1 += (a.x + a.y) + (a.z + a.w);
    s2 += (b.x + b.y) + (b.z + b.w);
    s3 += (c.x + c.y) + (c.z + c.w);
  }
  wave_reduce3(s1, s2, s3);
  __shared__ float l1[16], l2[16], l3[16];
  const int lane = tid & 63, wv = tid >> 6;
  if (lane == 0) { l1[wv] = s1; l2[wv] = s2; l3[wv] = s3; }
  __syncthreads();
  if (tid == 0) {
    float S1 = 0.f, S2 = 0.f, S3 = 0.f;
#pragma unroll
    for (int w = 0; w < 16; ++w) { S1 += l1[w]; S2 += l2[w]; S3 += l3[w]; }
    out[0] = MIU_ * fabsf(S1) + fabsf(S2) + S3 + ALPHA_ * (float)NTOT;
  }
}

extern "C" void kernel_launch(void* const* d_in, const int* in_sizes, int n_in,
                              void* d_out, int out_size, void* d_ws, size_t ws_size,
                              hipStream_t stream) {
  const float* pred  = (const float*)d_in[0];   // y_pred
  const float* truth = (const float*)d_in[1];   // y_true
  float* out      = (float*)d_out;
  float* partials = (float*)d_ws;               // 3*NBLK floats = 147 KB

  ace_main<<<NBLK, 256, 0, stream>>>(pred, truth, partials);
  ace_final<<<1, 1024, 0, stream>>>(partials, out);
}